// Round 10
// baseline (464.592 us; speedup 1.0000x reference)
//
#include <hip/hip_runtime.h>
#include <stdint.h>

#define FF 128
#define MFMA __builtin_amdgcn_mfma_f32_16x16x32_bf16

typedef __attribute__((ext_vector_type(8))) short bf8_t;     // 8 x bf16 MFMA frag
typedef __attribute__((ext_vector_type(4))) float f4_t;      // MFMA acc
typedef __attribute__((ext_vector_type(8))) uint16_t us8_t;  // 8 x bf16 bits

__device__ __forceinline__ uint16_t f2bf(float f) {
  union { float f; uint32_t u; } v; v.f = f;
  return (uint16_t)((v.u + 0x7fffu + ((v.u >> 16) & 1u)) >> 16);  // RNE
}
__device__ __forceinline__ float bf2f(uint16_t h) {
  union { uint32_t u; float f; } v; v.u = ((uint32_t)h) << 16;
  return v.f;
}

// Stage one 128x128 bf16 weight matrix (32KB) into LDS, chunk-major, 8 waves:
// wlds byte layout: k*1024, k = c*2 + (r>=64), c = 16B-col-chunk.
#define STAGE_W8(Wp, rsb, cb)                                                  \
  do {                                                                         \
    uint4 tmp_[4];                                                             \
    _Pragma("unroll") for (int j_ = 0; j_ < 4; ++j_) {                         \
      int k_ = j_ * 8 + w;                                                     \
      int r_ = ((k_ & 1) << 6) + lane;                                         \
      int c_ = k_ >> 1;                                                        \
      tmp_[j_] = *(const uint4*)((const char*)(Wp) + (size_t)r_ * (rsb) +      \
                                 (cb) + c_ * 16);                              \
    }                                                                          \
    _Pragma("unroll") for (int j_ = 0; j_ < 4; ++j_) {                         \
      int k_ = j_ * 8 + w;                                                     \
      *(uint4*)((char*)wlds + k_ * 1024 + lane * 16) = tmp_[j_];               \
    }                                                                          \
  } while (0)

// Stage TWO 128x128 bf16 matrices (W then G) into one 64KB LDS block, 8 waves.
#define STAGE2(Wp, Gp)                                                         \
  do {                                                                         \
    uint4 tmp_[8];                                                             \
    _Pragma("unroll") for (int j_ = 0; j_ < 8; ++j_) {                         \
      int k_ = j_ * 8 + w;                                                     \
      int cc_ = k_ & 31;                                                       \
      const char* sp_ = (j_ < 4) ? (const char*)(Wp) : (const char*)(Gp);      \
      int r_ = ((cc_ & 1) << 6) + lane;                                        \
      int c_ = cc_ >> 1;                                                       \
      tmp_[j_] = *(const uint4*)(sp_ + (size_t)r_ * 256 + c_ * 16);            \
    }                                                                          \
    _Pragma("unroll") for (int j_ = 0; j_ < 8; ++j_) {                         \
      int k_ = j_ * 8 + w;                                                     \
      *(uint4*)((char*)wlds + k_ * 1024 + lane * 16) = tmp_[j_];               \
    }                                                                          \
  } while (0)

#define WFRAG(s, t) (*(const bf8_t*)&wlds[((s)*4 + lg) * 1024 + ((t)*16 + lr) * 8])
#define GFRAG(s, t) \
  (*(const bf8_t*)&wlds[16384 + ((s)*4 + lg) * 1024 + ((t)*16 + lr) * 8])

// ---------------- weights f32 -> bf16 ----------------
// layout: [wsl | w1n | w2n | w1d | w2d] each 128x128
__global__ __launch_bounds__(256) void cvt_w_k(
    const float* __restrict__ wsl, const float* __restrict__ w1n,
    const float* __restrict__ w2n, const float* __restrict__ w1d,
    const float* __restrict__ w2d, uint16_t* __restrict__ o) {
  int i = blockIdx.x * 256 + threadIdx.x;
  if (i >= 5 * 16384) return;
  int wsel = i >> 14, j = i & 16383;
  const float* p = (wsel == 0) ? wsl : (wsel == 1) ? w1n : (wsel == 2) ? w2n
                   : (wsel == 3) ? w1d : w2d;
  o[i] = f2bf(p[j]);
}

// ---------------- gate pre-multiply: G_m = Wg_m @ W_m (128x128 f32 -> bf16) ----------------
__global__ __launch_bounds__(256) void gatepre_k(
    const float* __restrict__ wgat, const float* __restrict__ wsl,
    const float* __restrict__ w2n, const float* __restrict__ w2d,
    uint16_t* __restrict__ G) {
  const int mat = blockIdx.x >> 3;
  const int jblk = blockIdx.x & 7;
  const float* A = wgat + mat * 128;  // rows stride 384
  const float* B = (mat == 0) ? wsl : (mat == 1) ? w2n : w2d;
  const int i = threadIdx.x & 127;
  const int jo = jblk * 16 + (threadIdx.x >> 7) * 8;
  float acc[8] = {0.f, 0.f, 0.f, 0.f, 0.f, 0.f, 0.f, 0.f};
#pragma unroll 4
  for (int k = 0; k < 128; ++k) {
    float a = A[(size_t)i * 384 + k];
    const float* br = B + (size_t)k * 128 + jo;
#pragma unroll
    for (int j = 0; j < 8; ++j) acc[j] = fmaf(a, br[j], acc[j]);
  }
  uint16_t* g = G + mat * 16384 + i * 128 + jo;
#pragma unroll
  for (int j = 0; j < 8; ++j) g[j] = f2bf(acc[j]);
}

// bgat' = bgat + Wg0@b_sl + Wg1@b2n + Wg2@b2d
__global__ void bgatp_k(const float* __restrict__ wgat, const float* __restrict__ b_sl,
                        const float* __restrict__ b2n, const float* __restrict__ b2d,
                        const float* __restrict__ bgat, float* __restrict__ bgp) {
  int i = threadIdx.x;  // 128
  float s = bgat[i];
  for (int k = 0; k < 128; ++k) {
    s += wgat[(size_t)i * 384 + k] * b_sl[k];
    s += wgat[(size_t)i * 384 + 128 + k] * b2n[k];
    s += wgat[(size_t)i * 384 + 256 + k] * b2d[k];
  }
  bgp[i] = s;
}

// ---------------- x f32 -> bf16 ----------------
__global__ __launch_bounds__(256) void cvt_x_k(const float* __restrict__ x,
                                               uint16_t* __restrict__ xb, int n4) {
  int i = blockIdx.x * 256 + threadIdx.x;
  if (i >= n4) return;
  float4 v = ((const float4*)x)[i];
  uint2 o;
  o.x = ((uint32_t)f2bf(v.y) << 16) | f2bf(v.x);
  o.y = ((uint32_t)f2bf(v.w) << 16) | f2bf(v.z);
  ((uint2*)xb)[i] = o;
}

// ---------------- counting sort of edges by key = dst*2 + type ----------------
__global__ __launch_bounds__(256) void hist_k(const int* __restrict__ dst,
                                              const int* __restrict__ ety,
                                              int* __restrict__ hist, int E) {
  int i = blockIdx.x * 256 + threadIdx.x;
  if (i < E) atomicAdd(&hist[(dst[i] << 1) | ety[i]], 1);
}

__global__ __launch_bounds__(256) void scan1_k(const int* __restrict__ hist,
                                               int* __restrict__ off,
                                               int* __restrict__ bsum, int nbins) {
  int i = blockIdx.x * 256 + threadIdx.x;
  int v = (i < nbins) ? hist[i] : 0;
  int lane = threadIdx.x & 63, w = threadIdx.x >> 6;
  int s = v;
#pragma unroll
  for (int d = 1; d < 64; d <<= 1) {
    int o = __shfl_up(s, (unsigned)d, 64);
    if (lane >= d) s += o;
  }
  __shared__ int wsum[4];
  if (lane == 63) wsum[w] = s;
  __syncthreads();
  int add = 0;
  for (int k = 0; k < w; ++k) add += wsum[k];
  s += add;
  if (i < nbins) off[i] = s - v;  // exclusive
  if (threadIdx.x == 255) bsum[blockIdx.x] = s;
}

__global__ __launch_bounds__(1024) void scan2_k(int* __restrict__ bsum, int nb) {
  int t = threadIdx.x;
  int v = (t < nb) ? bsum[t] : 0;
  int lane = t & 63, w = t >> 6;
  int s = v;
#pragma unroll
  for (int d = 1; d < 64; d <<= 1) {
    int o = __shfl_up(s, (unsigned)d, 64);
    if (lane >= d) s += o;
  }
  __shared__ int ws[16];
  if (lane == 63) ws[w] = s;
  __syncthreads();
  int add = 0;
  for (int k = 0; k < w; ++k) add += ws[k];
  s += add;
  if (t < nb) bsum[t] = s - v;
}

// finalize fine offsets; also init coarse-bucket cursors ccur[b] = off[b*512]
__global__ __launch_bounds__(256) void scan3_k(int* __restrict__ off,
                                               int* __restrict__ ccur,
                                               const int* __restrict__ bsum,
                                               int nbins, int E) {
  int i = blockIdx.x * 256 + threadIdx.x;
  if (i < nbins) {
    int v = off[i] + bsum[blockIdx.x];
    off[i] = v;
    if ((i & 511) == 0) ccur[i >> 9] = v;
  }
  if (i == nbins) off[i] = E;
}

// ---------------- pass 1: LDS-aggregated coarse bucket scatter ----------------
#define BK_EPT 16
__global__ __launch_bounds__(256) void bucketize_k(const int* __restrict__ src,
                                                   const int* __restrict__ dst,
                                                   const int* __restrict__ ety,
                                                   int* __restrict__ ccur,
                                                   uint32_t* __restrict__ bk,
                                                   int E, int nbuckets) {
  __shared__ int lhist[512];
  __shared__ int lbase[512];
  const int tid = threadIdx.x;
  const int base = blockIdx.x * (256 * BK_EPT);
  for (int j = tid; j < nbuckets; j += 256) lhist[j] = 0;
  __syncthreads();

  uint32_t pk[BK_EPT];  // src | localbin<<17
  uint32_t rk[BK_EPT];  // bucket | rank<<9
#pragma unroll
  for (int j = 0; j < BK_EPT; ++j) {
    int i = base + j * 256 + tid;
    if (i < E) {
      int bin = (dst[i] << 1) | ety[i];
      int bucket = bin >> 9;
      int rank = atomicAdd(&lhist[bucket], 1);
      pk[j] = (uint32_t)src[i] | ((uint32_t)(bin & 511) << 17);
      rk[j] = (uint32_t)bucket | ((uint32_t)rank << 9);
    } else {
      rk[j] = 0xFFFFFFFFu;
    }
  }
  __syncthreads();
  for (int j = tid; j < nbuckets; j += 256) {
    int c = lhist[j];
    lbase[j] = c ? atomicAdd(&ccur[j], c) : 0;
  }
  __syncthreads();
#pragma unroll
  for (int j = 0; j < BK_EPT; ++j) {
    if (rk[j] != 0xFFFFFFFFu) {
      int bucket = (int)(rk[j] & 511u);
      int rank = (int)(rk[j] >> 9);
      bk[lbase[bucket] + rank] = pk[j];
    }
  }
}

// ---------------- pass 2: fine scatter within bucket (LDS cursors) ----------------
__global__ __launch_bounds__(256) void sctfine_k(const int* __restrict__ off,
                                                 const uint32_t* __restrict__ bk,
                                                 int* __restrict__ ssrc, int nbins) {
  __shared__ int lcur[512];
  const int b = blockIdx.x;
  const int binbase = b << 9;
  const int binend = min(binbase + 512, nbins);
  for (int j = threadIdx.x; j < binend - binbase; j += 256)
    lcur[j] = off[binbase + j];
  __syncthreads();
  const int estart = off[binbase], eend = off[binend];
  for (int i = estart + (int)threadIdx.x; i < eend; i += 256) {
    uint32_t pk = bk[i];
    int pos = atomicAdd(&lcur[pk >> 17], 1);
    ssrc[pos] = (int)(pk & 0x1FFFFu);
  }
}

// ---------------- segment-sum (bf16 gather) + own row: emits bf16 (x+agg) ----------------
__global__ __launch_bounds__(256) void agg_k(const int* __restrict__ off,
                                             const int* __restrict__ ssrc,
                                             const uint16_t* __restrict__ xb,
                                             const float* __restrict__ x,
                                             uint16_t* __restrict__ xanb,
                                             uint16_t* __restrict__ xadb, int nbins) {
  int wid = (blockIdx.x * 256 + threadIdx.x) >> 6;
  int lane = threadIdx.x & 63;
  if (wid >= nbins) return;
  int e = off[wid], end = off[wid + 1];
  float ax = 0.f, ay = 0.f, bx = 0.f, by = 0.f;
  for (; e + 7 < end; e += 8) {
    uint32_t v0 = ((const uint32_t*)(xb + (size_t)ssrc[e] * FF))[lane];
    uint32_t v1 = ((const uint32_t*)(xb + (size_t)ssrc[e + 1] * FF))[lane];
    uint32_t v2 = ((const uint32_t*)(xb + (size_t)ssrc[e + 2] * FF))[lane];
    uint32_t v3 = ((const uint32_t*)(xb + (size_t)ssrc[e + 3] * FF))[lane];
    uint32_t v4 = ((const uint32_t*)(xb + (size_t)ssrc[e + 4] * FF))[lane];
    uint32_t v5 = ((const uint32_t*)(xb + (size_t)ssrc[e + 5] * FF))[lane];
    uint32_t v6 = ((const uint32_t*)(xb + (size_t)ssrc[e + 6] * FF))[lane];
    uint32_t v7 = ((const uint32_t*)(xb + (size_t)ssrc[e + 7] * FF))[lane];
    ax += bf2f((uint16_t)(v0 & 0xffffu)) + bf2f((uint16_t)(v2 & 0xffffu)) +
          bf2f((uint16_t)(v4 & 0xffffu)) + bf2f((uint16_t)(v6 & 0xffffu));
    ay += bf2f((uint16_t)(v0 >> 16)) + bf2f((uint16_t)(v2 >> 16)) +
          bf2f((uint16_t)(v4 >> 16)) + bf2f((uint16_t)(v6 >> 16));
    bx += bf2f((uint16_t)(v1 & 0xffffu)) + bf2f((uint16_t)(v3 & 0xffffu)) +
          bf2f((uint16_t)(v5 & 0xffffu)) + bf2f((uint16_t)(v7 & 0xffffu));
    by += bf2f((uint16_t)(v1 >> 16)) + bf2f((uint16_t)(v3 >> 16)) +
          bf2f((uint16_t)(v5 >> 16)) + bf2f((uint16_t)(v7 >> 16));
  }
  for (; e + 1 < end; e += 2) {
    uint32_t v0 = ((const uint32_t*)(xb + (size_t)ssrc[e] * FF))[lane];
    uint32_t v1 = ((const uint32_t*)(xb + (size_t)ssrc[e + 1] * FF))[lane];
    ax += bf2f((uint16_t)(v0 & 0xffffu));
    ay += bf2f((uint16_t)(v0 >> 16));
    bx += bf2f((uint16_t)(v1 & 0xffffu));
    by += bf2f((uint16_t)(v1 >> 16));
  }
  if (e < end) {
    uint32_t v0 = ((const uint32_t*)(xb + (size_t)ssrc[e] * FF))[lane];
    ax += bf2f((uint16_t)(v0 & 0xffffu));
    ay += bf2f((uint16_t)(v0 >> 16));
  }
  ax += bx;
  ay += by;
  int n = wid >> 1;
  float2 xo = ((const float2*)(x + (size_t)n * FF))[lane];
  ax += xo.x;
  ay += xo.y;
  uint32_t o = ((uint32_t)f2bf(ay) << 16) | f2bf(ax);
  uint16_t* dstp = (wid & 1) ? xadb : xanb;
  ((uint32_t*)(dstp + (size_t)n * FF))[lane] = o;
}

// ---------------- stage 1: branch GEMM1s, 512 thr / 8 waves, 256 rows/block ----------------
__global__ __launch_bounds__(512) void gemm1_k(
    const uint16_t* __restrict__ xanb, const uint16_t* __restrict__ xadb,
    const uint16_t* __restrict__ wbf, const float* __restrict__ b1n,
    const float* __restrict__ b1d, uint16_t* __restrict__ h1n,
    uint16_t* __restrict__ h1d, float* __restrict__ gstats, int N) {
  __shared__ __align__(16) uint16_t wlds[16384];
  __shared__ float sstat[8][4][128];
  const int tid = threadIdx.x;
  const int lane = tid & 63, w = tid >> 6;
  const int lr = lane & 15, lg = lane >> 4;
  const int rowbase = blockIdx.x * 256 + w * 32;
  const int arow0 = min(rowbase + lr, N - 1);
  const int arow1 = min(rowbase + 16 + lr, N - 1);

  f4_t acc[2][8];
  const f4_t zz = {0.f, 0.f, 0.f, 0.f};
  bf8_t a0[4], a1[4];

  STAGE_W8(wbf + 16384, 256, 0);
#pragma unroll
  for (int s = 0; s < 4; ++s) {
    const int k0 = s * 32 + lg * 8;
    a0[s] = *(const bf8_t*)(xanb + (size_t)arow0 * FF + k0);
    a1[s] = *(const bf8_t*)(xanb + (size_t)arow1 * FF + k0);
  }
  __syncthreads();

#pragma unroll 1
  for (int gi = 0; gi < 2; ++gi) {
#pragma unroll
    for (int rg = 0; rg < 2; ++rg)
#pragma unroll
      for (int t = 0; t < 8; ++t) acc[rg][t] = zz;
#pragma unroll
    for (int s = 0; s < 4; ++s) {
#pragma unroll
      for (int t = 0; t < 8; ++t) {
        bf8_t b = WFRAG(s, t);
        acc[0][t] = MFMA(a0[s], b, acc[0][t], 0, 0, 0);
        acc[1][t] = MFMA(a1[s], b, acc[1][t], 0, 0, 0);
      }
    }
    const float* bp = gi ? b1d : b1n;
    uint16_t* hp = gi ? h1d : h1n;
#pragma unroll
    for (int t = 0; t < 8; ++t) {
      const int col = t * 16 + lr;
      const float b = bp[col];
      float sum = 0.f, ss = 0.f;
#pragma unroll
      for (int rg = 0; rg < 2; ++rg)
#pragma unroll
        for (int r = 0; r < 4; ++r) {
          const int row = rowbase + rg * 16 + lg * 4 + r;
          const float h = acc[rg][t][r] + b;
          if (row < N) {
            hp[(size_t)row * FF + col] = f2bf(h);
            sum += h;
            ss += h * h;
          }
        }
      sum += __shfl_xor(sum, 16, 64);
      sum += __shfl_xor(sum, 32, 64);
      ss += __shfl_xor(ss, 16, 64);
      ss += __shfl_xor(ss, 32, 64);
      if (lane < 16) {
        sstat[w][gi * 2 + 0][col] = sum;
        sstat[w][gi * 2 + 1][col] = ss;
      }
    }
    if (gi == 0) {
      __syncthreads();
      STAGE_W8(wbf + 3 * 16384, 256, 0);
#pragma unroll
      for (int s = 0; s < 4; ++s) {
        const int k0 = s * 32 + lg * 8;
        a0[s] = *(const bf8_t*)(xadb + (size_t)arow0 * FF + k0);
        a1[s] = *(const bf8_t*)(xadb + (size_t)arow1 * FF + k0);
      }
      __syncthreads();
    }
  }
  __syncthreads();
  if (tid < 512) {
    int a = tid >> 7, c = tid & 127;
    float v = 0.f;
#pragma unroll
    for (int ww = 0; ww < 8; ++ww) v += sstat[ww][a][c];
    unsafeAtomicAdd(&gstats[tid], v);
  }
}

// ---------------- BN finalize ----------------
__global__ void bnfin_k(const float* __restrict__ gstats,
                        const float* __restrict__ gamn, const float* __restrict__ betn,
                        const float* __restrict__ gamd, const float* __restrict__ betd,
                        float* __restrict__ bnp, int N) {
  int i = threadIdx.x;  // 128
  float invN = 1.f / (float)N;
  {
    float mu = gstats[i] * invN;
    float var = gstats[128 + i] * invN - mu * mu;
    float sc = gamn[i] * rsqrtf(var + 1e-5f);
    bnp[i] = sc;
    bnp[128 + i] = betn[i] - mu * sc;
  }
  {
    float mu = gstats[256 + i] * invN;
    float var = gstats[384 + i] * invN - mu * mu;
    float sc = gamd[i] * rsqrtf(var + 1e-5f);
    bnp[256 + i] = sc;
    bnp[384 + i] = betd[i] - mu * sc;
  }
}

// ---------------- stage 2: 3 fused phases (W ‖ pre-multiplied gate G), no smt ----------------
__global__ __launch_bounds__(512, 4) void fuse2_k(
    const uint16_t* __restrict__ xb, const uint16_t* __restrict__ h1n,
    const uint16_t* __restrict__ h1d, const uint16_t* __restrict__ wbf,
    const uint16_t* __restrict__ G, const float* __restrict__ bnp,
    const float* __restrict__ b_sl, const float* __restrict__ b2n,
    const float* __restrict__ b2d, const float* __restrict__ bgp,
    float* __restrict__ out, int N) {
  __shared__ __align__(16) uint16_t wlds[32768];  // 64KB: [W | G]
  const int tid = threadIdx.x;
  const int lane = tid & 63, w = tid >> 6;
  const int lr = lane & 15, lg = lane >> 4;
  const int rowbase = blockIdx.x * 128 + w * 16;
  const int arow = min(rowbase + lr, N - 1);

  f4_t sum[8];   // xx + xn running sum (f32, biases in)
  f4_t accG[8];  // gate logits (minus bgat')
  f4_t wk[8];    // per-branch work; after phase d holds xd+b2d
  const f4_t zz = {0.f, 0.f, 0.f, 0.f};

  // hoist A-row fragments
  bf8_t xa[4];
  us8_t hvn[4];
#pragma unroll
  for (int s = 0; s < 4; ++s) {
    const int k0 = s * 32 + lg * 8;
    xa[s] = *(const bf8_t*)(xb + (size_t)arow * FF + k0);
    hvn[s] = *(const us8_t*)(h1n + (size_t)arow * FF + k0);
  }

  STAGE2(wbf, G);  // wsl ‖ G0
  __syncthreads();

  // ---- phase 1: sum = xb@wsl^T + b_sl ; accG = xb@G0^T ----
#pragma unroll
  for (int t = 0; t < 8; ++t) { sum[t] = zz; accG[t] = zz; }
#pragma unroll
  for (int s = 0; s < 4; ++s) {
#pragma unroll
    for (int t = 0; t < 8; ++t) sum[t] = MFMA(xa[s], WFRAG(s, t), sum[t], 0, 0, 0);
#pragma unroll
    for (int t = 0; t < 8; ++t) accG[t] = MFMA(xa[s], GFRAG(s, t), accG[t], 0, 0, 0);
  }
#pragma unroll
  for (int t = 0; t < 8; ++t) {
    const float b = b_sl[t * 16 + lr];
#pragma unroll
    for (int r = 0; r < 4; ++r) sum[t][r] += b;
  }
  __syncthreads();

  STAGE2(wbf + 2 * 16384, G + 16384);  // w2n ‖ Gn
  us8_t hvd[4];
#pragma unroll
  for (int s = 0; s < 4; ++s)
    hvd[s] = *(const us8_t*)(h1d + (size_t)arow * FF + s * 32 + lg * 8);
  __syncthreads();

  // ---- phase 2: A_n = relu(bn(h1n)); sum += A_n@w2n^T + b2n ; accG += A_n@Gn^T ----
#pragma unroll
  for (int t = 0; t < 8; ++t) wk[t] = zz;
#pragma unroll
  for (int s = 0; s < 4; ++s) {
    const int k0 = s * 32 + lg * 8;
    f4_t sc0 = *(const f4_t*)(bnp + k0), sc1 = *(const f4_t*)(bnp + k0 + 4);
    f4_t sh0 = *(const f4_t*)(bnp + 128 + k0), sh1 = *(const f4_t*)(bnp + 128 + k0 + 4);
    bf8_t a;
#pragma unroll
    for (int j = 0; j < 4; ++j) {
      a[j] = (short)f2bf(fmaxf(bf2f(hvn[s][j]) * sc0[j] + sh0[j], 0.f));
      a[j + 4] = (short)f2bf(fmaxf(bf2f(hvn[s][j + 4]) * sc1[j] + sh1[j], 0.f));
    }
#pragma unroll
    for (int t = 0; t < 8; ++t) wk[t] = MFMA(a, WFRAG(s, t), wk[t], 0, 0, 0);
#pragma unroll
    for (int t = 0; t < 8; ++t) accG[t] = MFMA(a, GFRAG(s, t), accG[t], 0, 0, 0);
  }
#pragma unroll
  for (int t = 0; t < 8; ++t) {
    const float b = b2n[t * 16 + lr];
#pragma unroll
    for (int r = 0; r < 4; ++r) sum[t][r] += wk[t][r] + b;
  }
  __syncthreads();

  STAGE2(wbf + 4 * 16384, G + 2 * 16384);  // w2d ‖ Gd
  __syncthreads();

  // ---- phase 3: A_d; wk = A_d@w2d^T + b2d (kept for flip) ; accG += A_d@Gd^T ----
#pragma unroll
  for (int t = 0; t < 8; ++t) wk[t] = zz;
#pragma unroll
  for (int s = 0; s < 4; ++s) {
    const int k0 = s * 32 + lg * 8;
    const float* bnb = bnp + 256;
    f4_t sc0 = *(const f4_t*)(bnb + k0), sc1 = *(const f4_t*)(bnb + k0 + 4);
    f4_t sh0 = *(const f4_t*)(bnb + 128 + k0), sh1 = *(const f4_t*)(bnb + 128 + k0 + 4);
    bf8_t a;
#pragma unroll
    for (int j = 0; j < 4; ++j) {
      a[j] = (short)f2bf(fmaxf(bf2f(hvd[s][j]) * sc0[j] + sh0[j], 0.f));
      a[j + 4] = (short)f2bf(fmaxf(bf2f(hvd[s][j + 4]) * sc1[j] + sh1[j], 0.f));
    }
#pragma unroll
    for (int t = 0; t < 8; ++t) wk[t] = MFMA(a, WFRAG(s, t), wk[t], 0, 0, 0);
#pragma unroll
    for (int t = 0; t < 8; ++t) accG[t] = MFMA(a, GFRAG(s, t), accG[t], 0, 0, 0);
  }
#pragma unroll
  for (int t = 0; t < 8; ++t) {
    const float b = b2d[t * 16 + lr];
#pragma unroll
    for (int r = 0; r < 4; ++r) wk[t][r] += b;
  }

  // ---- softmax + cumsum + output; flip(xd) is a register permutation:
  // (row, 127-col) lives at register 7-t, lane lr^15 (same row group).
  float bg[8];
#pragma unroll
  for (int t = 0; t < 8; ++t) bg[t] = bgp[t * 16 + lr];
#pragma unroll
  for (int r = 0; r < 4; ++r) {
    float lv[8];
#pragma unroll
    for (int t = 0; t < 8; ++t) lv[t] = accG[t][r] + bg[t];
    float m = lv[0];
#pragma unroll
    for (int t = 1; t < 8; ++t) m = fmaxf(m, lv[t]);
#pragma unroll
    for (int d = 1; d < 16; d <<= 1) m = fmaxf(m, __shfl_xor(m, d, 16));
    float g[8];
    float run = 0.f;
#pragma unroll
    for (int t = 0; t < 8; ++t) {
      float p = __expf(lv[t] - m);
      float scn = p;
#pragma unroll
      for (int d = 1; d < 16; d <<= 1) {
        float o = __shfl_up(scn, (unsigned)d, 16);
        if (lr >= d) scn += o;
      }
      g[t] = run + scn;
      run += __shfl(scn, 15, 16);
    }
    const float inv = 1.f / run;
    float xdf[8];
#pragma unroll
    for (int t = 0; t < 8; ++t) xdf[t] = __shfl_xor(wk[7 - t][r], 15, 64);
    const int row = rowbase + lg * 4 + r;
    if (row < N) {
#pragma unroll
      for (int t = 0; t < 8; ++t)
        out[(size_t)row * FF + t * 16 + lr] = sum[t][r] + xdf[t] * (g[t] * inv);
    }
  }
}

extern "C" void kernel_launch(void* const* d_in, const int* in_sizes, int n_in,
                              void* d_out, int out_size, void* d_ws, size_t ws_size,
                              hipStream_t stream) {
  const float* x = (const float*)d_in[0];
  const int* eidx = (const int*)d_in[1];
  const int* etype = (const int*)d_in[2];
  const float* w_sl = (const float*)d_in[3];
  const float* b_sl = (const float*)d_in[4];
  const float* w1n = (const float*)d_in[5];
  const float* b1n = (const float*)d_in[6];
  const float* gamn = (const float*)d_in[7];
  const float* betn = (const float*)d_in[8];
  const float* w2n = (const float*)d_in[9];
  const float* b2n = (const float*)d_in[10];
  const float* w1d = (const float*)d_in[11];
  const float* b1d = (const float*)d_in[12];
  const float* gamd = (const float*)d_in[13];
  const float* betd = (const float*)d_in[14];
  const float* w2d = (const float*)d_in[15];
  const float* b2d = (const float*)d_in[16];
  const float* wgat = (const float*)d_in[17];
  const float* bgat = (const float*)d_in[18];
  float* out = (float*)d_out;

  const int N = in_sizes[0] / FF;
  const int E = in_sizes[2];
  const int* src = eidx;
  const int* dst = eidx + E;
  const int nbins = 2 * N;
  const int nbuckets = (nbins + 511) >> 9;

  const size_t NF = (size_t)N * FF;
  float* gstats = (float*)d_ws;               // 512
  float* bnp = gstats + 512;                  // 512
  float* bgp = bnp + 512;                     // 128
  uint16_t* wbf = (uint16_t*)(bgp + 128);     // 5*16384 u16
  uint16_t* G = wbf + 5 * 16384;              // 3*16384 u16
  uint16_t* xb = G + 3 * 16384;               // NF
  uint16_t* xanb = xb + NF;
  uint16_t* xadb = xanb + NF;
  uint16_t* h1n = xadb + NF;
  uint16_t* h1d = h1n + NF;
  int* hist = (int*)(h1d + NF);
  int* off = hist + nbins;        // nbins+1
  int* ccur = off + nbins + 1;    // nbuckets
  int* bsum = ccur + nbuckets;    // <=1024
  int* ssrc = bsum + 1024;        // E
  uint32_t* bk = (uint32_t*)(ssrc + E);  // E

  const int nb1 = (nbins + 255) / 256;

  hipMemsetAsync(hist, 0, (size_t)nbins * sizeof(int), stream);
  hipMemsetAsync(gstats, 0, 512 * sizeof(float), stream);
  cvt_w_k<<<320, 256, 0, stream>>>(w_sl, w1n, w2n, w1d, w2d, wbf);
  cvt_x_k<<<(int)((NF / 4 + 255) / 256), 256, 0, stream>>>(x, xb, (int)(NF / 4));
  gatepre_k<<<24, 256, 0, stream>>>(wgat, w_sl, w2n, w2d, G);
  bgatp_k<<<1, 128, 0, stream>>>(wgat, b_sl, b2n, b2d, bgat, bgp);

  hist_k<<<(E + 255) / 256, 256, 0, stream>>>(dst, etype, hist, E);
  scan1_k<<<nb1, 256, 0, stream>>>(hist, off, bsum, nbins);
  scan2_k<<<1, 1024, 0, stream>>>(bsum, nb1);
  scan3_k<<<(nbins + 256) / 256, 256, 0, stream>>>(off, ccur, bsum, nbins, E);
  bucketize_k<<<(E + 256 * BK_EPT - 1) / (256 * BK_EPT), 256, 0, stream>>>(
      src, dst, etype, ccur, bk, E, nbuckets);
  sctfine_k<<<nbuckets, 256, 0, stream>>>(off, bk, ssrc, nbins);
  agg_k<<<(nbins + 3) / 4, 256, 0, stream>>>(off, ssrc, xb, x, xanb, xadb, nbins);

  gemm1_k<<<(N + 255) / 256, 512, 0, stream>>>(xanb, xadb, wbf, b1n, b1d, h1n, h1d,
                                               gstats, N);
  bnfin_k<<<1, 128, 0, stream>>>(gstats, gamn, betn, gamd, betd, bnp, N);
  fuse2_k<<<(N + 127) / 128, 512, 0, stream>>>(xb, h1n, h1d, wbf, G, bnp, b_sl,
                                               b2n, b2d, bgp, out, N);
}

// Round 11
// 387.582 us; speedup vs baseline: 1.1987x; 1.1987x over previous
//
#include <hip/hip_runtime.h>
#include <stdint.h>

#define FF 128
#define MFMA __builtin_amdgcn_mfma_f32_16x16x32_bf16

typedef __attribute__((ext_vector_type(8))) short bf8_t;     // 8 x bf16 MFMA frag
typedef __attribute__((ext_vector_type(4))) float f4_t;      // MFMA acc
typedef __attribute__((ext_vector_type(8))) uint16_t us8_t;  // 8 x bf16 bits

__device__ __forceinline__ uint16_t f2bf(float f) {
  union { float f; uint32_t u; } v; v.f = f;
  return (uint16_t)((v.u + 0x7fffu + ((v.u >> 16) & 1u)) >> 16);  // RNE
}
__device__ __forceinline__ float bf2f(uint16_t h) {
  union { uint32_t u; float f; } v; v.u = ((uint32_t)h) << 16;
  return v.f;
}

// Stage one 128x128 bf16 weight matrix (32KB) into LDS, chunk-major, 8 waves:
#define STAGE_W8(Wp, rsb, cb)                                                  \
  do {                                                                         \
    uint4 tmp_[4];                                                             \
    _Pragma("unroll") for (int j_ = 0; j_ < 4; ++j_) {                         \
      int k_ = j_ * 8 + w;                                                     \
      int r_ = ((k_ & 1) << 6) + lane;                                         \
      int c_ = k_ >> 1;                                                        \
      tmp_[j_] = *(const uint4*)((const char*)(Wp) + (size_t)r_ * (rsb) +      \
                                 (cb) + c_ * 16);                              \
    }                                                                          \
    _Pragma("unroll") for (int j_ = 0; j_ < 4; ++j_) {                         \
      int k_ = j_ * 8 + w;                                                     \
      *(uint4*)((char*)wlds + k_ * 1024 + lane * 16) = tmp_[j_];               \
    }                                                                          \
  } while (0)

// Stage TWO 128x128 bf16 matrices (W then G) into one 64KB LDS block, 8 waves.
#define STAGE2(Wp, Gp)                                                         \
  do {                                                                         \
    uint4 tmp_[8];                                                             \
    _Pragma("unroll") for (int j_ = 0; j_ < 8; ++j_) {                         \
      int k_ = j_ * 8 + w;                                                     \
      int cc_ = k_ & 31;                                                       \
      const char* sp_ = (j_ < 4) ? (const char*)(Wp) : (const char*)(Gp);      \
      int r_ = ((cc_ & 1) << 6) + lane;                                        \
      int c_ = cc_ >> 1;                                                       \
      tmp_[j_] = *(const uint4*)(sp_ + (size_t)r_ * 256 + c_ * 16);            \
    }                                                                          \
    _Pragma("unroll") for (int j_ = 0; j_ < 8; ++j_) {                         \
      int k_ = j_ * 8 + w;                                                     \
      *(uint4*)((char*)wlds + k_ * 1024 + lane * 16) = tmp_[j_];               \
    }                                                                          \
  } while (0)

#define WFRAG(s, t) (*(const bf8_t*)&wlds[((s)*4 + lg) * 1024 + ((t)*16 + lr) * 8])
#define GFRAG(s, t) \
  (*(const bf8_t*)&wlds[16384 + ((s)*4 + lg) * 1024 + ((t)*16 + lr) * 8])

// ---------------- weights f32 -> bf16 ----------------
__global__ __launch_bounds__(256) void cvt_w_k(
    const float* __restrict__ wsl, const float* __restrict__ w1n,
    const float* __restrict__ w2n, const float* __restrict__ w1d,
    const float* __restrict__ w2d, uint16_t* __restrict__ o) {
  int i = blockIdx.x * 256 + threadIdx.x;
  if (i >= 5 * 16384) return;
  int wsel = i >> 14, j = i & 16383;
  const float* p = (wsel == 0) ? wsl : (wsel == 1) ? w1n : (wsel == 2) ? w2n
                   : (wsel == 3) ? w1d : w2d;
  o[i] = f2bf(p[j]);
}

// ---------------- gate pre-multiply: G_m = Wg_m @ W_m (128x128 f32 -> bf16) ----------------
__global__ __launch_bounds__(256) void gatepre_k(
    const float* __restrict__ wgat, const float* __restrict__ wsl,
    const float* __restrict__ w2n, const float* __restrict__ w2d,
    uint16_t* __restrict__ G) {
  const int mat = blockIdx.x >> 3;
  const int jblk = blockIdx.x & 7;
  const float* A = wgat + mat * 128;  // rows stride 384
  const float* B = (mat == 0) ? wsl : (mat == 1) ? w2n : w2d;
  const int i = threadIdx.x & 127;
  const int jo = jblk * 16 + (threadIdx.x >> 7) * 8;
  float acc[8] = {0.f, 0.f, 0.f, 0.f, 0.f, 0.f, 0.f, 0.f};
#pragma unroll 4
  for (int k = 0; k < 128; ++k) {
    float a = A[(size_t)i * 384 + k];
    const float* br = B + (size_t)k * 128 + jo;
#pragma unroll
    for (int j = 0; j < 8; ++j) acc[j] = fmaf(a, br[j], acc[j]);
  }
  uint16_t* g = G + mat * 16384 + i * 128 + jo;
#pragma unroll
  for (int j = 0; j < 8; ++j) g[j] = f2bf(acc[j]);
}

// bgat' = bgat + Wg0@b_sl + Wg1@b2n + Wg2@b2d
__global__ void bgatp_k(const float* __restrict__ wgat, const float* __restrict__ b_sl,
                        const float* __restrict__ b2n, const float* __restrict__ b2d,
                        const float* __restrict__ bgat, float* __restrict__ bgp) {
  int i = threadIdx.x;  // 128
  float s = bgat[i];
  for (int k = 0; k < 128; ++k) {
    s += wgat[(size_t)i * 384 + k] * b_sl[k];
    s += wgat[(size_t)i * 384 + 128 + k] * b2n[k];
    s += wgat[(size_t)i * 384 + 256 + k] * b2d[k];
  }
  bgp[i] = s;
}

// ---------------- x f32 -> bf16 ----------------
__global__ __launch_bounds__(256) void cvt_x_k(const float* __restrict__ x,
                                               uint16_t* __restrict__ xb, int n4) {
  int i = blockIdx.x * 256 + threadIdx.x;
  if (i >= n4) return;
  float4 v = ((const float4*)x)[i];
  uint2 o;
  o.x = ((uint32_t)f2bf(v.y) << 16) | f2bf(v.x);
  o.y = ((uint32_t)f2bf(v.w) << 16) | f2bf(v.z);
  ((uint2*)xb)[i] = o;
}

// ---------------- counting sort of edges by key = dst*2 + type ----------------
__global__ __launch_bounds__(256) void hist_k(const int* __restrict__ dst,
                                              const int* __restrict__ ety,
                                              int* __restrict__ hist, int E) {
  int i = blockIdx.x * 256 + threadIdx.x;
  if (i < E) atomicAdd(&hist[(dst[i] << 1) | ety[i]], 1);
}

__global__ __launch_bounds__(256) void scan1_k(const int* __restrict__ hist,
                                               int* __restrict__ off,
                                               int* __restrict__ bsum, int nbins) {
  int i = blockIdx.x * 256 + threadIdx.x;
  int v = (i < nbins) ? hist[i] : 0;
  int lane = threadIdx.x & 63, w = threadIdx.x >> 6;
  int s = v;
#pragma unroll
  for (int d = 1; d < 64; d <<= 1) {
    int o = __shfl_up(s, (unsigned)d, 64);
    if (lane >= d) s += o;
  }
  __shared__ int wsum[4];
  if (lane == 63) wsum[w] = s;
  __syncthreads();
  int add = 0;
  for (int k = 0; k < w; ++k) add += wsum[k];
  s += add;
  if (i < nbins) off[i] = s - v;  // exclusive
  if (threadIdx.x == 255) bsum[blockIdx.x] = s;
}

__global__ __launch_bounds__(1024) void scan2_k(int* __restrict__ bsum, int nb) {
  int t = threadIdx.x;
  int v = (t < nb) ? bsum[t] : 0;
  int lane = t & 63, w = t >> 6;
  int s = v;
#pragma unroll
  for (int d = 1; d < 64; d <<= 1) {
    int o = __shfl_up(s, (unsigned)d, 64);
    if (lane >= d) s += o;
  }
  __shared__ int ws[16];
  if (lane == 63) ws[w] = s;
  __syncthreads();
  int add = 0;
  for (int k = 0; k < w; ++k) add += ws[k];
  s += add;
  if (t < nb) bsum[t] = s - v;
}

// finalize fine offsets; also init coarse-bucket cursors ccur[b] = off[b*512]
__global__ __launch_bounds__(256) void scan3_k(int* __restrict__ off,
                                               int* __restrict__ ccur,
                                               const int* __restrict__ bsum,
                                               int nbins, int E) {
  int i = blockIdx.x * 256 + threadIdx.x;
  if (i < nbins) {
    int v = off[i] + bsum[blockIdx.x];
    off[i] = v;
    if ((i & 511) == 0) ccur[i >> 9] = v;
  }
  if (i == nbins) off[i] = E;
}

// ---------------- pass 1: LDS-aggregated coarse bucket scatter ----------------
#define BK_EPT 16
__global__ __launch_bounds__(256) void bucketize_k(const int* __restrict__ src,
                                                   const int* __restrict__ dst,
                                                   const int* __restrict__ ety,
                                                   int* __restrict__ ccur,
                                                   uint32_t* __restrict__ bk,
                                                   int E, int nbuckets) {
  __shared__ int lhist[512];
  __shared__ int lbase[512];
  const int tid = threadIdx.x;
  const int base = blockIdx.x * (256 * BK_EPT);
  for (int j = tid; j < nbuckets; j += 256) lhist[j] = 0;
  __syncthreads();

  uint32_t pk[BK_EPT];  // src | localbin<<17
  uint32_t rk[BK_EPT];  // bucket | rank<<9
#pragma unroll
  for (int j = 0; j < BK_EPT; ++j) {
    int i = base + j * 256 + tid;
    if (i < E) {
      int bin = (dst[i] << 1) | ety[i];
      int bucket = bin >> 9;
      int rank = atomicAdd(&lhist[bucket], 1);
      pk[j] = (uint32_t)src[i] | ((uint32_t)(bin & 511) << 17);
      rk[j] = (uint32_t)bucket | ((uint32_t)rank << 9);
    } else {
      rk[j] = 0xFFFFFFFFu;
    }
  }
  __syncthreads();
  for (int j = tid; j < nbuckets; j += 256) {
    int c = lhist[j];
    lbase[j] = c ? atomicAdd(&ccur[j], c) : 0;
  }
  __syncthreads();
#pragma unroll
  for (int j = 0; j < BK_EPT; ++j) {
    if (rk[j] != 0xFFFFFFFFu) {
      int bucket = (int)(rk[j] & 511u);
      int rank = (int)(rk[j] >> 9);
      bk[lbase[bucket] + rank] = pk[j];
    }
  }
}

// ---------------- pass 2: fine scatter within bucket (LDS cursors) ----------------
__global__ __launch_bounds__(256) void sctfine_k(const int* __restrict__ off,
                                                 const uint32_t* __restrict__ bk,
                                                 int* __restrict__ ssrc, int nbins) {
  __shared__ int lcur[512];
  const int b = blockIdx.x;
  const int binbase = b << 9;
  const int binend = min(binbase + 512, nbins);
  for (int j = threadIdx.x; j < binend - binbase; j += 256)
    lcur[j] = off[binbase + j];
  __syncthreads();
  const int estart = off[binbase], eend = off[binend];
  for (int i = estart + (int)threadIdx.x; i < eend; i += 256) {
    uint32_t pk = bk[i];
    int pos = atomicAdd(&lcur[pk >> 17], 1);
    ssrc[pos] = (int)(pk & 0x1FFFFu);
  }
}

// ---------------- segment-sum (bf16 gather) + own row: emits bf16 (x+agg) ----------------
__global__ __launch_bounds__(256) void agg_k(const int* __restrict__ off,
                                             const int* __restrict__ ssrc,
                                             const uint16_t* __restrict__ xb,
                                             const float* __restrict__ x,
                                             uint16_t* __restrict__ xanb,
                                             uint16_t* __restrict__ xadb, int nbins) {
  int wid = (blockIdx.x * 256 + threadIdx.x) >> 6;
  int lane = threadIdx.x & 63;
  if (wid >= nbins) return;
  int e = off[wid], end = off[wid + 1];
  float ax = 0.f, ay = 0.f, bx = 0.f, by = 0.f;
  for (; e + 7 < end; e += 8) {
    uint32_t v0 = ((const uint32_t*)(xb + (size_t)ssrc[e] * FF))[lane];
    uint32_t v1 = ((const uint32_t*)(xb + (size_t)ssrc[e + 1] * FF))[lane];
    uint32_t v2 = ((const uint32_t*)(xb + (size_t)ssrc[e + 2] * FF))[lane];
    uint32_t v3 = ((const uint32_t*)(xb + (size_t)ssrc[e + 3] * FF))[lane];
    uint32_t v4 = ((const uint32_t*)(xb + (size_t)ssrc[e + 4] * FF))[lane];
    uint32_t v5 = ((const uint32_t*)(xb + (size_t)ssrc[e + 5] * FF))[lane];
    uint32_t v6 = ((const uint32_t*)(xb + (size_t)ssrc[e + 6] * FF))[lane];
    uint32_t v7 = ((const uint32_t*)(xb + (size_t)ssrc[e + 7] * FF))[lane];
    ax += bf2f((uint16_t)(v0 & 0xffffu)) + bf2f((uint16_t)(v2 & 0xffffu)) +
          bf2f((uint16_t)(v4 & 0xffffu)) + bf2f((uint16_t)(v6 & 0xffffu));
    ay += bf2f((uint16_t)(v0 >> 16)) + bf2f((uint16_t)(v2 >> 16)) +
          bf2f((uint16_t)(v4 >> 16)) + bf2f((uint16_t)(v6 >> 16));
    bx += bf2f((uint16_t)(v1 & 0xffffu)) + bf2f((uint16_t)(v3 & 0xffffu)) +
          bf2f((uint16_t)(v5 & 0xffffu)) + bf2f((uint16_t)(v7 & 0xffffu));
    by += bf2f((uint16_t)(v1 >> 16)) + bf2f((uint16_t)(v3 >> 16)) +
          bf2f((uint16_t)(v5 >> 16)) + bf2f((uint16_t)(v7 >> 16));
  }
  for (; e + 1 < end; e += 2) {
    uint32_t v0 = ((const uint32_t*)(xb + (size_t)ssrc[e] * FF))[lane];
    uint32_t v1 = ((const uint32_t*)(xb + (size_t)ssrc[e + 1] * FF))[lane];
    ax += bf2f((uint16_t)(v0 & 0xffffu));
    ay += bf2f((uint16_t)(v0 >> 16));
    bx += bf2f((uint16_t)(v1 & 0xffffu));
    by += bf2f((uint16_t)(v1 >> 16));
  }
  if (e < end) {
    uint32_t v0 = ((const uint32_t*)(xb + (size_t)ssrc[e] * FF))[lane];
    ax += bf2f((uint16_t)(v0 & 0xffffu));
    ay += bf2f((uint16_t)(v0 >> 16));
  }
  ax += bx;
  ay += by;
  int n = wid >> 1;
  float2 xo = ((const float2*)(x + (size_t)n * FF))[lane];
  ax += xo.x;
  ay += xo.y;
  uint32_t o = ((uint32_t)f2bf(ay) << 16) | f2bf(ax);
  uint16_t* dstp = (wid & 1) ? xadb : xanb;
  ((uint32_t*)(dstp + (size_t)n * FF))[lane] = o;
}

// ---------------- stage 1: branch GEMM1s, 512 thr / 8 waves, 256 rows/block ----------------
__global__ __launch_bounds__(512) void gemm1_k(
    const uint16_t* __restrict__ xanb, const uint16_t* __restrict__ xadb,
    const uint16_t* __restrict__ wbf, const float* __restrict__ b1n,
    const float* __restrict__ b1d, uint16_t* __restrict__ h1n,
    uint16_t* __restrict__ h1d, float* __restrict__ gstats, int N) {
  __shared__ __align__(16) uint16_t wlds[16384];
  __shared__ float sstat[8][4][128];
  const int tid = threadIdx.x;
  const int lane = tid & 63, w = tid >> 6;
  const int lr = lane & 15, lg = lane >> 4;
  const int rowbase = blockIdx.x * 256 + w * 32;
  const int arow0 = min(rowbase + lr, N - 1);
  const int arow1 = min(rowbase + 16 + lr, N - 1);

  f4_t acc[2][8];
  const f4_t zz = {0.f, 0.f, 0.f, 0.f};
  bf8_t a0[4], a1[4];

  STAGE_W8(wbf + 16384, 256, 0);
#pragma unroll
  for (int s = 0; s < 4; ++s) {
    const int k0 = s * 32 + lg * 8;
    a0[s] = *(const bf8_t*)(xanb + (size_t)arow0 * FF + k0);
    a1[s] = *(const bf8_t*)(xanb + (size_t)arow1 * FF + k0);
  }
  __syncthreads();

#pragma unroll 1
  for (int gi = 0; gi < 2; ++gi) {
#pragma unroll
    for (int rg = 0; rg < 2; ++rg)
#pragma unroll
      for (int t = 0; t < 8; ++t) acc[rg][t] = zz;
#pragma unroll
    for (int s = 0; s < 4; ++s) {
#pragma unroll
      for (int t = 0; t < 8; ++t) {
        bf8_t b = WFRAG(s, t);
        acc[0][t] = MFMA(a0[s], b, acc[0][t], 0, 0, 0);
        acc[1][t] = MFMA(a1[s], b, acc[1][t], 0, 0, 0);
      }
    }
    const float* bp = gi ? b1d : b1n;
    uint16_t* hp = gi ? h1d : h1n;
#pragma unroll
    for (int t = 0; t < 8; ++t) {
      const int col = t * 16 + lr;
      const float b = bp[col];
      float sum = 0.f, ss = 0.f;
#pragma unroll
      for (int rg = 0; rg < 2; ++rg)
#pragma unroll
        for (int r = 0; r < 4; ++r) {
          const int row = rowbase + rg * 16 + lg * 4 + r;
          const float h = acc[rg][t][r] + b;
          if (row < N) {
            hp[(size_t)row * FF + col] = f2bf(h);
            sum += h;
            ss += h * h;
          }
        }
      sum += __shfl_xor(sum, 16, 64);
      sum += __shfl_xor(sum, 32, 64);
      ss += __shfl_xor(ss, 16, 64);
      ss += __shfl_xor(ss, 32, 64);
      if (lane < 16) {
        sstat[w][gi * 2 + 0][col] = sum;
        sstat[w][gi * 2 + 1][col] = ss;
      }
    }
    if (gi == 0) {
      __syncthreads();
      STAGE_W8(wbf + 3 * 16384, 256, 0);
#pragma unroll
      for (int s = 0; s < 4; ++s) {
        const int k0 = s * 32 + lg * 8;
        a0[s] = *(const bf8_t*)(xadb + (size_t)arow0 * FF + k0);
        a1[s] = *(const bf8_t*)(xadb + (size_t)arow1 * FF + k0);
      }
      __syncthreads();
    }
  }
  __syncthreads();
  if (tid < 512) {
    int a = tid >> 7, c = tid & 127;
    float v = 0.f;
#pragma unroll
    for (int ww = 0; ww < 8; ++ww) v += sstat[ww][a][c];
    unsafeAtomicAdd(&gstats[tid], v);
  }
}

// ---------------- BN finalize ----------------
__global__ void bnfin_k(const float* __restrict__ gstats,
                        const float* __restrict__ gamn, const float* __restrict__ betn,
                        const float* __restrict__ gamd, const float* __restrict__ betd,
                        float* __restrict__ bnp, int N) {
  int i = threadIdx.x;  // 128
  float invN = 1.f / (float)N;
  {
    float mu = gstats[i] * invN;
    float var = gstats[128 + i] * invN - mu * mu;
    float sc = gamn[i] * rsqrtf(var + 1e-5f);
    bnp[i] = sc;
    bnp[128 + i] = betn[i] - mu * sc;
  }
  {
    float mu = gstats[256 + i] * invN;
    float var = gstats[384 + i] * invN - mu * mu;
    float sc = gamd[i] * rsqrtf(var + 1e-5f);
    bnp[256 + i] = sc;
    bnp[384 + i] = betd[i] - mu * sc;
  }
}

// ---------------- stage 2: 3 fused phases (W ‖ pre-multiplied gate G), no smt ----------------
__global__ __launch_bounds__(512) void fuse2_k(
    const uint16_t* __restrict__ xb, const uint16_t* __restrict__ h1n,
    const uint16_t* __restrict__ h1d, const uint16_t* __restrict__ wbf,
    const uint16_t* __restrict__ G, const float* __restrict__ bnp,
    const float* __restrict__ b_sl, const float* __restrict__ b2n,
    const float* __restrict__ b2d, const float* __restrict__ bgp,
    float* __restrict__ out, int N) {
  __shared__ __align__(16) uint16_t wlds[32768];  // 64KB: [W | G]
  const int tid = threadIdx.x;
  const int lane = tid & 63, w = tid >> 6;
  const int lr = lane & 15, lg = lane >> 4;
  const int rowbase = blockIdx.x * 128 + w * 16;
  const int arow = min(rowbase + lr, N - 1);

  f4_t sum[8];   // xx + xn running sum (f32, biases in)
  f4_t accG[8];  // gate logits (minus bgat')
  f4_t wk[8];    // per-branch work; after phase d holds xd+b2d
  const f4_t zz = {0.f, 0.f, 0.f, 0.f};

  // hoist A-row fragments
  bf8_t xa[4];
  us8_t hvn[4];
#pragma unroll
  for (int s = 0; s < 4; ++s) {
    const int k0 = s * 32 + lg * 8;
    xa[s] = *(const bf8_t*)(xb + (size_t)arow * FF + k0);
    hvn[s] = *(const us8_t*)(h1n + (size_t)arow * FF + k0);
  }

  STAGE2(wbf, G);  // wsl ‖ G0
  __syncthreads();

  // ---- phase 1: sum = xb@wsl^T + b_sl ; accG = xb@G0^T ----
#pragma unroll
  for (int t = 0; t < 8; ++t) { sum[t] = zz; accG[t] = zz; }
#pragma unroll
  for (int s = 0; s < 4; ++s) {
#pragma unroll
    for (int t = 0; t < 8; ++t) sum[t] = MFMA(xa[s], WFRAG(s, t), sum[t], 0, 0, 0);
#pragma unroll
    for (int t = 0; t < 8; ++t) accG[t] = MFMA(xa[s], GFRAG(s, t), accG[t], 0, 0, 0);
  }
#pragma unroll
  for (int t = 0; t < 8; ++t) {
    const float b = b_sl[t * 16 + lr];
#pragma unroll
    for (int r = 0; r < 4; ++r) sum[t][r] += b;
  }
  __syncthreads();

  STAGE2(wbf + 2 * 16384, G + 16384);  // w2n ‖ Gn
  us8_t hvd[4];
#pragma unroll
  for (int s = 0; s < 4; ++s)
    hvd[s] = *(const us8_t*)(h1d + (size_t)arow * FF + s * 32 + lg * 8);
  __syncthreads();

  // ---- phase 2: A_n = relu(bn(h1n)); sum += A_n@w2n^T + b2n ; accG += A_n@Gn^T ----
#pragma unroll
  for (int t = 0; t < 8; ++t) wk[t] = zz;
#pragma unroll
  for (int s = 0; s < 4; ++s) {
    const int k0 = s * 32 + lg * 8;
    f4_t sc0 = *(const f4_t*)(bnp + k0), sc1 = *(const f4_t*)(bnp + k0 + 4);
    f4_t sh0 = *(const f4_t*)(bnp + 128 + k0), sh1 = *(const f4_t*)(bnp + 128 + k0 + 4);
    bf8_t a;
#pragma unroll
    for (int j = 0; j < 4; ++j) {
      a[j] = (short)f2bf(fmaxf(bf2f(hvn[s][j]) * sc0[j] + sh0[j], 0.f));
      a[j + 4] = (short)f2bf(fmaxf(bf2f(hvn[s][j + 4]) * sc1[j] + sh1[j], 0.f));
    }
#pragma unroll
    for (int t = 0; t < 8; ++t) wk[t] = MFMA(a, WFRAG(s, t), wk[t], 0, 0, 0);
#pragma unroll
    for (int t = 0; t < 8; ++t) accG[t] = MFMA(a, GFRAG(s, t), accG[t], 0, 0, 0);
  }
#pragma unroll
  for (int t = 0; t < 8; ++t) {
    const float b = b2n[t * 16 + lr];
#pragma unroll
    for (int r = 0; r < 4; ++r) sum[t][r] += wk[t][r] + b;
  }
  __syncthreads();

  STAGE2(wbf + 4 * 16384, G + 2 * 16384);  // w2d ‖ Gd
  __syncthreads();

  // ---- phase 3: A_d; wk = A_d@w2d^T + b2d (kept for flip) ; accG += A_d@Gd^T ----
#pragma unroll
  for (int t = 0; t < 8; ++t) wk[t] = zz;
#pragma unroll
  for (int s = 0; s < 4; ++s) {
    const int k0 = s * 32 + lg * 8;
    const float* bnb = bnp + 256;
    f4_t sc0 = *(const f4_t*)(bnb + k0), sc1 = *(const f4_t*)(bnb + k0 + 4);
    f4_t sh0 = *(const f4_t*)(bnb + 128 + k0), sh1 = *(const f4_t*)(bnb + 128 + k0 + 4);
    bf8_t a;
#pragma unroll
    for (int j = 0; j < 4; ++j) {
      a[j] = (short)f2bf(fmaxf(bf2f(hvd[s][j]) * sc0[j] + sh0[j], 0.f));
      a[j + 4] = (short)f2bf(fmaxf(bf2f(hvd[s][j + 4]) * sc1[j] + sh1[j], 0.f));
    }
#pragma unroll
    for (int t = 0; t < 8; ++t) wk[t] = MFMA(a, WFRAG(s, t), wk[t], 0, 0, 0);
#pragma unroll
    for (int t = 0; t < 8; ++t) accG[t] = MFMA(a, GFRAG(s, t), accG[t], 0, 0, 0);
  }
#pragma unroll
  for (int t = 0; t < 8; ++t) {
    const float b = b2d[t * 16 + lr];
#pragma unroll
    for (int r = 0; r < 4; ++r) wk[t][r] += b;
  }

  // ---- softmax + cumsum + output; flip(xd) is a register permutation:
  // (row, 127-col) lives at register 7-t, lane lr^15 (same row group).
  float bg[8];
#pragma unroll
  for (int t = 0; t < 8; ++t) bg[t] = bgp[t * 16 + lr];
#pragma unroll
  for (int r = 0; r < 4; ++r) {
    float lv[8];
#pragma unroll
    for (int t = 0; t < 8; ++t) lv[t] = accG[t][r] + bg[t];
    float m = lv[0];
#pragma unroll
    for (int t = 1; t < 8; ++t) m = fmaxf(m, lv[t]);
#pragma unroll
    for (int d = 1; d < 16; d <<= 1) m = fmaxf(m, __shfl_xor(m, d, 16));
    float g[8];
    float run = 0.f;
#pragma unroll
    for (int t = 0; t < 8; ++t) {
      float p = __expf(lv[t] - m);
      float scn = p;
#pragma unroll
      for (int d = 1; d < 16; d <<= 1) {
        float o = __shfl_up(scn, (unsigned)d, 16);
        if (lr >= d) scn += o;
      }
      g[t] = run + scn;
      run += __shfl(scn, 15, 16);
    }
    const float inv = 1.f / run;
    float xdf[8];
#pragma unroll
    for (int t = 0; t < 8; ++t) xdf[t] = __shfl_xor(wk[7 - t][r], 15, 64);
    const int row = rowbase + lg * 4 + r;
    if (row < N) {
#pragma unroll
      for (int t = 0; t < 8; ++t)
        out[(size_t)row * FF + t * 16 + lr] = sum[t][r] + xdf[t] * (g[t] * inv);
    }
  }
}

extern "C" void kernel_launch(void* const* d_in, const int* in_sizes, int n_in,
                              void* d_out, int out_size, void* d_ws, size_t ws_size,
                              hipStream_t stream) {
  const float* x = (const float*)d_in[0];
  const int* eidx = (const int*)d_in[1];
  const int* etype = (const int*)d_in[2];
  const float* w_sl = (const float*)d_in[3];
  const float* b_sl = (const float*)d_in[4];
  const float* w1n = (const float*)d_in[5];
  const float* b1n = (const float*)d_in[6];
  const float* gamn = (const float*)d_in[7];
  const float* betn = (const float*)d_in[8];
  const float* w2n = (const float*)d_in[9];
  const float* b2n = (const float*)d_in[10];
  const float* w1d = (const float*)d_in[11];
  const float* b1d = (const float*)d_in[12];
  const float* gamd = (const float*)d_in[13];
  const float* betd = (const float*)d_in[14];
  const float* w2d = (const float*)d_in[15];
  const float* b2d = (const float*)d_in[16];
  const float* wgat = (const float*)d_in[17];
  const float* bgat = (const float*)d_in[18];
  float* out = (float*)d_out;

  const int N = in_sizes[0] / FF;
  const int E = in_sizes[2];
  const int* src = eidx;
  const int* dst = eidx + E;
  const int nbins = 2 * N;
  const int nbuckets = (nbins + 511) >> 9;

  const size_t NF = (size_t)N * FF;
  float* gstats = (float*)d_ws;               // 512
  float* bnp = gstats + 512;                  // 512
  float* bgp = bnp + 512;                     // 128
  uint16_t* wbf = (uint16_t*)(bgp + 128);     // 5*16384 u16
  uint16_t* G = wbf + 5 * 16384;              // 3*16384 u16
  uint16_t* xb = G + 3 * 16384;               // NF
  uint16_t* xanb = xb + NF;
  uint16_t* xadb = xanb + NF;
  uint16_t* h1n = xadb + NF;
  uint16_t* h1d = h1n + NF;
  int* hist = (int*)(h1d + NF);
  int* off = hist + nbins;        // nbins+1
  int* ccur = off + nbins + 1;    // nbuckets
  int* bsum = ccur + nbuckets;    // <=1024
  int* ssrc = bsum + 1024;        // E
  uint32_t* bk = (uint32_t*)(ssrc + E);  // E

  const int nb1 = (nbins + 255) / 256;

  hipMemsetAsync(hist, 0, (size_t)nbins * sizeof(int), stream);
  hipMemsetAsync(gstats, 0, 512 * sizeof(float), stream);
  cvt_w_k<<<320, 256, 0, stream>>>(w_sl, w1n, w2n, w1d, w2d, wbf);
  cvt_x_k<<<(int)((NF / 4 + 255) / 256), 256, 0, stream>>>(x, xb, (int)(NF / 4));
  gatepre_k<<<24, 256, 0, stream>>>(wgat, w_sl, w2n, w2d, G);
  bgatp_k<<<1, 128, 0, stream>>>(wgat, b_sl, b2n, b2d, bgat, bgp);

  hist_k<<<(E + 255) / 256, 256, 0, stream>>>(dst, etype, hist, E);
  scan1_k<<<nb1, 256, 0, stream>>>(hist, off, bsum, nbins);
  scan2_k<<<1, 1024, 0, stream>>>(bsum, nb1);
  scan3_k<<<(nbins + 256) / 256, 256, 0, stream>>>(off, ccur, bsum, nbins, E);
  bucketize_k<<<(E + 256 * BK_EPT - 1) / (256 * BK_EPT), 256, 0, stream>>>(
      src, dst, etype, ccur, bk, E, nbuckets);
  sctfine_k<<<nbuckets, 256, 0, stream>>>(off, bk, ssrc, nbins);
  agg_k<<<(nbins + 3) / 4, 256, 0, stream>>>(off, ssrc, xb, x, xanb, xadb, nbins);

  gemm1_k<<<(N + 255) / 256, 512, 0, stream>>>(xanb, xadb, wbf, b1n, b1d, h1n, h1d,
                                               gstats, N);
  bnfin_k<<<1, 128, 0, stream>>>(gstats, gamn, betn, gamd, betd, bnp, N);
  fuse2_k<<<(N + 127) / 128, 512, 0, stream>>>(xb, h1n, h1d, wbf, G, bnp, b_sl,
                                               b2n, b2d, bgp, out, N);
}

// Round 12
// 376.874 us; speedup vs baseline: 1.2328x; 1.0284x over previous
//
#include <hip/hip_runtime.h>
#include <stdint.h>

#define FF 128
#define MFMA __builtin_amdgcn_mfma_f32_16x16x32_bf16

typedef __attribute__((ext_vector_type(8))) short bf8_t;     // 8 x bf16 MFMA frag
typedef __attribute__((ext_vector_type(4))) float f4_t;      // MFMA acc
typedef __attribute__((ext_vector_type(8))) uint16_t us8_t;  // 8 x bf16 bits

__device__ __forceinline__ uint16_t f2bf(float f) {
  union { float f; uint32_t u; } v; v.f = f;
  return (uint16_t)((v.u + 0x7fffu + ((v.u >> 16) & 1u)) >> 16);  // RNE
}
__device__ __forceinline__ float bf2f(uint16_t h) {
  union { uint32_t u; float f; } v; v.u = ((uint32_t)h) << 16;
  return v.f;
}

// Stage one 128x128 bf16 weight matrix (32KB) into LDS, chunk-major, 8 waves:
#define STAGE_W8(Wp, rsb, cb)                                                  \
  do {                                                                         \
    uint4 tmp_[4];                                                             \
    _Pragma("unroll") for (int j_ = 0; j_ < 4; ++j_) {                         \
      int k_ = j_ * 8 + w;                                                     \
      int r_ = ((k_ & 1) << 6) + lane;                                         \
      int c_ = k_ >> 1;                                                        \
      tmp_[j_] = *(const uint4*)((const char*)(Wp) + (size_t)r_ * (rsb) +      \
                                 (cb) + c_ * 16);                              \
    }                                                                          \
    _Pragma("unroll") for (int j_ = 0; j_ < 4; ++j_) {                         \
      int k_ = j_ * 8 + w;                                                     \
      *(uint4*)((char*)wlds + k_ * 1024 + lane * 16) = tmp_[j_];               \
    }                                                                          \
  } while (0)

// Stage TWO 128x128 bf16 matrices (W then G) into one 64KB LDS block, 8 waves.
#define STAGE2(Wp, Gp)                                                         \
  do {                                                                         \
    uint4 tmp_[8];                                                             \
    _Pragma("unroll") for (int j_ = 0; j_ < 8; ++j_) {                         \
      int k_ = j_ * 8 + w;                                                     \
      int cc_ = k_ & 31;                                                       \
      const char* sp_ = (j_ < 4) ? (const char*)(Wp) : (const char*)(Gp);      \
      int r_ = ((cc_ & 1) << 6) + lane;                                        \
      int c_ = cc_ >> 1;                                                       \
      tmp_[j_] = *(const uint4*)(sp_ + (size_t)r_ * 256 + c_ * 16);            \
    }                                                                          \
    _Pragma("unroll") for (int j_ = 0; j_ < 8; ++j_) {                         \
      int k_ = j_ * 8 + w;                                                     \
      *(uint4*)((char*)wlds + k_ * 1024 + lane * 16) = tmp_[j_];               \
    }                                                                          \
  } while (0)

#define WFRAG(s, t) (*(const bf8_t*)&wlds[((s)*4 + lg) * 1024 + ((t)*16 + lr) * 8])
#define GFRAG(s, t) \
  (*(const bf8_t*)&wlds[16384 + ((s)*4 + lg) * 1024 + ((t)*16 + lr) * 8])

// ---------------- weights f32 -> bf16 ----------------
__global__ __launch_bounds__(256) void cvt_w_k(
    const float* __restrict__ wsl, const float* __restrict__ w1n,
    const float* __restrict__ w2n, const float* __restrict__ w1d,
    const float* __restrict__ w2d, uint16_t* __restrict__ o) {
  int i = blockIdx.x * 256 + threadIdx.x;
  if (i >= 5 * 16384) return;
  int wsel = i >> 14, j = i & 16383;
  const float* p = (wsel == 0) ? wsl : (wsel == 1) ? w1n : (wsel == 2) ? w2n
                   : (wsel == 3) ? w1d : w2d;
  o[i] = f2bf(p[j]);
}

// ---------------- gate pre-multiply: G_m = Wg_m @ W_m (128x128 f32 -> bf16) ----------------
__global__ __launch_bounds__(256) void gatepre_k(
    const float* __restrict__ wgat, const float* __restrict__ wsl,
    const float* __restrict__ w2n, const float* __restrict__ w2d,
    uint16_t* __restrict__ G) {
  const int mat = blockIdx.x >> 3;
  const int jblk = blockIdx.x & 7;
  const float* A = wgat + mat * 128;  // rows stride 384
  const float* B = (mat == 0) ? wsl : (mat == 1) ? w2n : w2d;
  const int i = threadIdx.x & 127;
  const int jo = jblk * 16 + (threadIdx.x >> 7) * 8;
  float acc[8] = {0.f, 0.f, 0.f, 0.f, 0.f, 0.f, 0.f, 0.f};
#pragma unroll 4
  for (int k = 0; k < 128; ++k) {
    float a = A[(size_t)i * 384 + k];
    const float* br = B + (size_t)k * 128 + jo;
#pragma unroll
    for (int j = 0; j < 8; ++j) acc[j] = fmaf(a, br[j], acc[j]);
  }
  uint16_t* g = G + mat * 16384 + i * 128 + jo;
#pragma unroll
  for (int j = 0; j < 8; ++j) g[j] = f2bf(acc[j]);
}

// bgat' = bgat + Wg0@b_sl + Wg1@b2n + Wg2@b2d
__global__ void bgatp_k(const float* __restrict__ wgat, const float* __restrict__ b_sl,
                        const float* __restrict__ b2n, const float* __restrict__ b2d,
                        const float* __restrict__ bgat, float* __restrict__ bgp) {
  int i = threadIdx.x;  // 128
  float s = bgat[i];
  for (int k = 0; k < 128; ++k) {
    s += wgat[(size_t)i * 384 + k] * b_sl[k];
    s += wgat[(size_t)i * 384 + 128 + k] * b2n[k];
    s += wgat[(size_t)i * 384 + 256 + k] * b2d[k];
  }
  bgp[i] = s;
}

// ---------------- x f32 -> bf16 ----------------
__global__ __launch_bounds__(256) void cvt_x_k(const float* __restrict__ x,
                                               uint16_t* __restrict__ xb, int n4) {
  int i = blockIdx.x * 256 + threadIdx.x;
  if (i >= n4) return;
  float4 v = ((const float4*)x)[i];
  uint2 o;
  o.x = ((uint32_t)f2bf(v.y) << 16) | f2bf(v.x);
  o.y = ((uint32_t)f2bf(v.w) << 16) | f2bf(v.z);
  ((uint2*)xb)[i] = o;
}

// ---------------- counting sort of edges by key = dst*2 + type ----------------
__global__ __launch_bounds__(256) void hist_k(const int* __restrict__ dst,
                                              const int* __restrict__ ety,
                                              int* __restrict__ hist, int E) {
  int i = blockIdx.x * 256 + threadIdx.x;
  if (i < E) atomicAdd(&hist[(dst[i] << 1) | ety[i]], 1);
}

__global__ __launch_bounds__(256) void scan1_k(const int* __restrict__ hist,
                                               int* __restrict__ off,
                                               int* __restrict__ bsum, int nbins) {
  int i = blockIdx.x * 256 + threadIdx.x;
  int v = (i < nbins) ? hist[i] : 0;
  int lane = threadIdx.x & 63, w = threadIdx.x >> 6;
  int s = v;
#pragma unroll
  for (int d = 1; d < 64; d <<= 1) {
    int o = __shfl_up(s, (unsigned)d, 64);
    if (lane >= d) s += o;
  }
  __shared__ int wsum[4];
  if (lane == 63) wsum[w] = s;
  __syncthreads();
  int add = 0;
  for (int k = 0; k < w; ++k) add += wsum[k];
  s += add;
  if (i < nbins) off[i] = s - v;  // exclusive
  if (threadIdx.x == 255) bsum[blockIdx.x] = s;
}

__global__ __launch_bounds__(1024) void scan2_k(int* __restrict__ bsum, int nb) {
  int t = threadIdx.x;
  int v = (t < nb) ? bsum[t] : 0;
  int lane = t & 63, w = t >> 6;
  int s = v;
#pragma unroll
  for (int d = 1; d < 64; d <<= 1) {
    int o = __shfl_up(s, (unsigned)d, 64);
    if (lane >= d) s += o;
  }
  __shared__ int ws[16];
  if (lane == 63) ws[w] = s;
  __syncthreads();
  int add = 0;
  for (int k = 0; k < w; ++k) add += ws[k];
  s += add;
  if (t < nb) bsum[t] = s - v;
}

// finalize fine offsets; also init coarse-bucket cursors ccur[b] = off[b*512]
__global__ __launch_bounds__(256) void scan3_k(int* __restrict__ off,
                                               int* __restrict__ ccur,
                                               const int* __restrict__ bsum,
                                               int nbins, int E) {
  int i = blockIdx.x * 256 + threadIdx.x;
  if (i < nbins) {
    int v = off[i] + bsum[blockIdx.x];
    off[i] = v;
    if ((i & 511) == 0) ccur[i >> 9] = v;
  }
  if (i == nbins) off[i] = E;
}

// ---------------- pass 1: LDS-aggregated coarse bucket scatter ----------------
#define BK_EPT 16
__global__ __launch_bounds__(256) void bucketize_k(const int* __restrict__ src,
                                                   const int* __restrict__ dst,
                                                   const int* __restrict__ ety,
                                                   int* __restrict__ ccur,
                                                   uint32_t* __restrict__ bk,
                                                   int E, int nbuckets) {
  __shared__ int lhist[512];
  __shared__ int lbase[512];
  const int tid = threadIdx.x;
  const int base = blockIdx.x * (256 * BK_EPT);
  for (int j = tid; j < nbuckets; j += 256) lhist[j] = 0;
  __syncthreads();

  uint32_t pk[BK_EPT];  // src | localbin<<17
  uint32_t rk[BK_EPT];  // bucket | rank<<9
#pragma unroll
  for (int j = 0; j < BK_EPT; ++j) {
    int i = base + j * 256 + tid;
    if (i < E) {
      int bin = (dst[i] << 1) | ety[i];
      int bucket = bin >> 9;
      int rank = atomicAdd(&lhist[bucket], 1);
      pk[j] = (uint32_t)src[i] | ((uint32_t)(bin & 511) << 17);
      rk[j] = (uint32_t)bucket | ((uint32_t)rank << 9);
    } else {
      rk[j] = 0xFFFFFFFFu;
    }
  }
  __syncthreads();
  for (int j = tid; j < nbuckets; j += 256) {
    int c = lhist[j];
    lbase[j] = c ? atomicAdd(&ccur[j], c) : 0;
  }
  __syncthreads();
#pragma unroll
  for (int j = 0; j < BK_EPT; ++j) {
    if (rk[j] != 0xFFFFFFFFu) {
      int bucket = (int)(rk[j] & 511u);
      int rank = (int)(rk[j] >> 9);
      bk[lbase[bucket] + rank] = pk[j];
    }
  }
}

// ---------------- pass 2: fine scatter within bucket (LDS cursors) ----------------
__global__ __launch_bounds__(256) void sctfine_k(const int* __restrict__ off,
                                                 const uint32_t* __restrict__ bk,
                                                 int* __restrict__ ssrc, int nbins) {
  __shared__ int lcur[512];
  const int b = blockIdx.x;
  const int binbase = b << 9;
  const int binend = min(binbase + 512, nbins);
  for (int j = threadIdx.x; j < binend - binbase; j += 256)
    lcur[j] = off[binbase + j];
  __syncthreads();
  const int estart = off[binbase], eend = off[binend];
  for (int i = estart + (int)threadIdx.x; i < eend; i += 256) {
    uint32_t pk = bk[i];
    int pos = atomicAdd(&lcur[pk >> 17], 1);
    ssrc[pos] = (int)(pk & 0x1FFFFu);
  }
}

// ---------------- segment-sum: quad-row bf16 gather (4 rows per load instr) ----------------
// Wave layout: lane = q*16 + c; quarter q handles row e+q, chunk c = 16B (8 cols).
__global__ __launch_bounds__(256) void agg_k(const int* __restrict__ off,
                                             const int* __restrict__ ssrc,
                                             const uint16_t* __restrict__ xb,
                                             uint16_t* __restrict__ xanb,
                                             uint16_t* __restrict__ xadb, int nbins) {
  int wid = (blockIdx.x * 256 + threadIdx.x) >> 6;
  int lane = threadIdx.x & 63;
  if (wid >= nbins) return;
  const int q = lane >> 4, c = lane & 15;
  int e = off[wid], end = off[wid + 1];
  float acc[8] = {0.f, 0.f, 0.f, 0.f, 0.f, 0.f, 0.f, 0.f};

#define ACC8(v)                                                       \
  do {                                                                \
    union { uint32_t u; float f; } lo_, hi_;                          \
    lo_.u = (v).x << 16; hi_.u = (v).x & 0xffff0000u;                 \
    acc[0] += lo_.f; acc[1] += hi_.f;                                 \
    lo_.u = (v).y << 16; hi_.u = (v).y & 0xffff0000u;                 \
    acc[2] += lo_.f; acc[3] += hi_.f;                                 \
    lo_.u = (v).z << 16; hi_.u = (v).z & 0xffff0000u;                 \
    acc[4] += lo_.f; acc[5] += hi_.f;                                 \
    lo_.u = (v).w << 16; hi_.u = (v).w & 0xffff0000u;                 \
    acc[6] += lo_.f; acc[7] += hi_.f;                                 \
  } while (0)

  for (; e + 8 <= end; e += 8) {
    int s0 = ssrc[e + q];
    int s1 = ssrc[e + 4 + q];
    uint4 v0 = *(const uint4*)(xb + (size_t)s0 * FF + c * 8);
    uint4 v1 = *(const uint4*)(xb + (size_t)s1 * FF + c * 8);
    ACC8(v0);
    ACC8(v1);
  }
  for (; e + 4 <= end; e += 4) {
    int s0 = ssrc[e + q];
    uint4 v0 = *(const uint4*)(xb + (size_t)s0 * FF + c * 8);
    ACC8(v0);
  }
  int r = end - e;
  if (r > 0) {
    int s0 = ssrc[e + min(q, r - 1)];
    uint4 v0 = *(const uint4*)(xb + (size_t)s0 * FF + c * 8);
    if (q < r) ACC8(v0);
  }
#undef ACC8

  // fold quarters: lanes {c, c+16, c+32, c+48} hold partials for same 8 cols
#pragma unroll
  for (int j = 0; j < 8; ++j) {
    acc[j] += __shfl_xor(acc[j], 16, 64);
    acc[j] += __shfl_xor(acc[j], 32, 64);
  }
  const int n = wid >> 1;
  // add own row (bf16)
  uint4 own = *(const uint4*)(xb + (size_t)n * FF + c * 8);
  {
    union { uint32_t u; float f; } lo_, hi_;
    lo_.u = own.x << 16; hi_.u = own.x & 0xffff0000u;
    acc[0] += lo_.f; acc[1] += hi_.f;
    lo_.u = own.y << 16; hi_.u = own.y & 0xffff0000u;
    acc[2] += lo_.f; acc[3] += hi_.f;
    lo_.u = own.z << 16; hi_.u = own.z & 0xffff0000u;
    acc[4] += lo_.f; acc[5] += hi_.f;
    lo_.u = own.w << 16; hi_.u = own.w & 0xffff0000u;
    acc[6] += lo_.f; acc[7] += hi_.f;
  }
  if (q == 0) {
    uint4 o;
    o.x = ((uint32_t)f2bf(acc[1]) << 16) | f2bf(acc[0]);
    o.y = ((uint32_t)f2bf(acc[3]) << 16) | f2bf(acc[2]);
    o.z = ((uint32_t)f2bf(acc[5]) << 16) | f2bf(acc[4]);
    o.w = ((uint32_t)f2bf(acc[7]) << 16) | f2bf(acc[6]);
    uint16_t* dstp = (wid & 1) ? xadb : xanb;
    *(uint4*)(dstp + (size_t)n * FF + c * 8) = o;
  }
}

// ---------------- stage 1: branch GEMM1s, 512 thr / 8 waves, 256 rows/block ----------------
__global__ __launch_bounds__(512) void gemm1_k(
    const uint16_t* __restrict__ xanb, const uint16_t* __restrict__ xadb,
    const uint16_t* __restrict__ wbf, const float* __restrict__ b1n,
    const float* __restrict__ b1d, uint16_t* __restrict__ h1n,
    uint16_t* __restrict__ h1d, float* __restrict__ gstats, int N) {
  __shared__ __align__(16) uint16_t wlds[16384];
  __shared__ float sstat[8][4][128];
  const int tid = threadIdx.x;
  const int lane = tid & 63, w = tid >> 6;
  const int lr = lane & 15, lg = lane >> 4;
  const int rowbase = blockIdx.x * 256 + w * 32;
  const int arow0 = min(rowbase + lr, N - 1);
  const int arow1 = min(rowbase + 16 + lr, N - 1);

  f4_t acc[2][8];
  const f4_t zz = {0.f, 0.f, 0.f, 0.f};
  bf8_t a0[4], a1[4];

  STAGE_W8(wbf + 16384, 256, 0);
#pragma unroll
  for (int s = 0; s < 4; ++s) {
    const int k0 = s * 32 + lg * 8;
    a0[s] = *(const bf8_t*)(xanb + (size_t)arow0 * FF + k0);
    a1[s] = *(const bf8_t*)(xanb + (size_t)arow1 * FF + k0);
  }
  __syncthreads();

#pragma unroll 1
  for (int gi = 0; gi < 2; ++gi) {
#pragma unroll
    for (int rg = 0; rg < 2; ++rg)
#pragma unroll
      for (int t = 0; t < 8; ++t) acc[rg][t] = zz;
#pragma unroll
    for (int s = 0; s < 4; ++s) {
#pragma unroll
      for (int t = 0; t < 8; ++t) {
        bf8_t b = WFRAG(s, t);
        acc[0][t] = MFMA(a0[s], b, acc[0][t], 0, 0, 0);
        acc[1][t] = MFMA(a1[s], b, acc[1][t], 0, 0, 0);
      }
    }
    const float* bp = gi ? b1d : b1n;
    uint16_t* hp = gi ? h1d : h1n;
#pragma unroll
    for (int t = 0; t < 8; ++t) {
      const int col = t * 16 + lr;
      const float b = bp[col];
      float sum = 0.f, ss = 0.f;
#pragma unroll
      for (int rg = 0; rg < 2; ++rg)
#pragma unroll
        for (int r = 0; r < 4; ++r) {
          const int row = rowbase + rg * 16 + lg * 4 + r;
          const float h = acc[rg][t][r] + b;
          if (row < N) {
            hp[(size_t)row * FF + col] = f2bf(h);
            sum += h;
            ss += h * h;
          }
        }
      sum += __shfl_xor(sum, 16, 64);
      sum += __shfl_xor(sum, 32, 64);
      ss += __shfl_xor(ss, 16, 64);
      ss += __shfl_xor(ss, 32, 64);
      if (lane < 16) {
        sstat[w][gi * 2 + 0][col] = sum;
        sstat[w][gi * 2 + 1][col] = ss;
      }
    }
    if (gi == 0) {
      __syncthreads();
      STAGE_W8(wbf + 3 * 16384, 256, 0);
#pragma unroll
      for (int s = 0; s < 4; ++s) {
        const int k0 = s * 32 + lg * 8;
        a0[s] = *(const bf8_t*)(xadb + (size_t)arow0 * FF + k0);
        a1[s] = *(const bf8_t*)(xadb + (size_t)arow1 * FF + k0);
      }
      __syncthreads();
    }
  }
  __syncthreads();
  if (tid < 512) {
    int a = tid >> 7, c = tid & 127;
    float v = 0.f;
#pragma unroll
    for (int ww = 0; ww < 8; ++ww) v += sstat[ww][a][c];
    unsafeAtomicAdd(&gstats[tid], v);
  }
}

// ---------------- BN finalize ----------------
__global__ void bnfin_k(const float* __restrict__ gstats,
                        const float* __restrict__ gamn, const float* __restrict__ betn,
                        const float* __restrict__ gamd, const float* __restrict__ betd,
                        float* __restrict__ bnp, int N) {
  int i = threadIdx.x;  // 128
  float invN = 1.f / (float)N;
  {
    float mu = gstats[i] * invN;
    float var = gstats[128 + i] * invN - mu * mu;
    float sc = gamn[i] * rsqrtf(var + 1e-5f);
    bnp[i] = sc;
    bnp[128 + i] = betn[i] - mu * sc;
  }
  {
    float mu = gstats[256 + i] * invN;
    float var = gstats[384 + i] * invN - mu * mu;
    float sc = gamd[i] * rsqrtf(var + 1e-5f);
    bnp[256 + i] = sc;
    bnp[384 + i] = betd[i] - mu * sc;
  }
}

// ---------------- stage 2: 3 fused phases (W ‖ pre-multiplied gate G), no smt ----------------
__global__ __launch_bounds__(512) void fuse2_k(
    const uint16_t* __restrict__ xb, const uint16_t* __restrict__ h1n,
    const uint16_t* __restrict__ h1d, const uint16_t* __restrict__ wbf,
    const uint16_t* __restrict__ G, const float* __restrict__ bnp,
    const float* __restrict__ b_sl, const float* __restrict__ b2n,
    const float* __restrict__ b2d, const float* __restrict__ bgp,
    float* __restrict__ out, int N) {
  __shared__ __align__(16) uint16_t wlds[32768];  // 64KB: [W | G]
  const int tid = threadIdx.x;
  const int lane = tid & 63, w = tid >> 6;
  const int lr = lane & 15, lg = lane >> 4;
  const int rowbase = blockIdx.x * 128 + w * 16;
  const int arow = min(rowbase + lr, N - 1);

  f4_t sum[8];   // xx + xn running sum (f32, biases in)
  f4_t accG[8];  // gate logits (minus bgat')
  f4_t wk[8];    // per-branch work; after phase d holds xd+b2d
  const f4_t zz = {0.f, 0.f, 0.f, 0.f};

  // hoist A-row fragments
  bf8_t xa[4];
  us8_t hvn[4];
#pragma unroll
  for (int s = 0; s < 4; ++s) {
    const int k0 = s * 32 + lg * 8;
    xa[s] = *(const bf8_t*)(xb + (size_t)arow * FF + k0);
    hvn[s] = *(const us8_t*)(h1n + (size_t)arow * FF + k0);
  }

  STAGE2(wbf, G);  // wsl ‖ G0
  __syncthreads();

  // ---- phase 1: sum = xb@wsl^T + b_sl ; accG = xb@G0^T ----
#pragma unroll
  for (int t = 0; t < 8; ++t) { sum[t] = zz; accG[t] = zz; }
#pragma unroll
  for (int s = 0; s < 4; ++s) {
#pragma unroll
    for (int t = 0; t < 8; ++t) sum[t] = MFMA(xa[s], WFRAG(s, t), sum[t], 0, 0, 0);
#pragma unroll
    for (int t = 0; t < 8; ++t) accG[t] = MFMA(xa[s], GFRAG(s, t), accG[t], 0, 0, 0);
  }
#pragma unroll
  for (int t = 0; t < 8; ++t) {
    const float b = b_sl[t * 16 + lr];
#pragma unroll
    for (int r = 0; r < 4; ++r) sum[t][r] += b;
  }
  __syncthreads();

  STAGE2(wbf + 2 * 16384, G + 16384);  // w2n ‖ Gn
  us8_t hvd[4];
#pragma unroll
  for (int s = 0; s < 4; ++s)
    hvd[s] = *(const us8_t*)(h1d + (size_t)arow * FF + s * 32 + lg * 8);
  __syncthreads();

  // ---- phase 2: A_n = relu(bn(h1n)); sum += A_n@w2n^T + b2n ; accG += A_n@Gn^T ----
#pragma unroll
  for (int t = 0; t < 8; ++t) wk[t] = zz;
#pragma unroll
  for (int s = 0; s < 4; ++s) {
    const int k0 = s * 32 + lg * 8;
    f4_t sc0 = *(const f4_t*)(bnp + k0), sc1 = *(const f4_t*)(bnp + k0 + 4);
    f4_t sh0 = *(const f4_t*)(bnp + 128 + k0), sh1 = *(const f4_t*)(bnp + 128 + k0 + 4);
    bf8_t a;
#pragma unroll
    for (int j = 0; j < 4; ++j) {
      a[j] = (short)f2bf(fmaxf(bf2f(hvn[s][j]) * sc0[j] + sh0[j], 0.f));
      a[j + 4] = (short)f2bf(fmaxf(bf2f(hvn[s][j + 4]) * sc1[j] + sh1[j], 0.f));
    }
#pragma unroll
    for (int t = 0; t < 8; ++t) wk[t] = MFMA(a, WFRAG(s, t), wk[t], 0, 0, 0);
#pragma unroll
    for (int t = 0; t < 8; ++t) accG[t] = MFMA(a, GFRAG(s, t), accG[t], 0, 0, 0);
  }
#pragma unroll
  for (int t = 0; t < 8; ++t) {
    const float b = b2n[t * 16 + lr];
#pragma unroll
    for (int r = 0; r < 4; ++r) sum[t][r] += wk[t][r] + b;
  }
  __syncthreads();

  STAGE2(wbf + 4 * 16384, G + 2 * 16384);  // w2d ‖ Gd
  __syncthreads();

  // ---- phase 3: A_d; wk = A_d@w2d^T + b2d (kept for flip) ; accG += A_d@Gd^T ----
#pragma unroll
  for (int t = 0; t < 8; ++t) wk[t] = zz;
#pragma unroll
  for (int s = 0; s < 4; ++s) {
    const int k0 = s * 32 + lg * 8;
    const float* bnb = bnp + 256;
    f4_t sc0 = *(const f4_t*)(bnb + k0), sc1 = *(const f4_t*)(bnb + k0 + 4);
    f4_t sh0 = *(const f4_t*)(bnb + 128 + k0), sh1 = *(const f4_t*)(bnb + 128 + k0 + 4);
    bf8_t a;
#pragma unroll
    for (int j = 0; j < 4; ++j) {
      a[j] = (short)f2bf(fmaxf(bf2f(hvd[s][j]) * sc0[j] + sh0[j], 0.f));
      a[j + 4] = (short)f2bf(fmaxf(bf2f(hvd[s][j + 4]) * sc1[j] + sh1[j], 0.f));
    }
#pragma unroll
    for (int t = 0; t < 8; ++t) wk[t] = MFMA(a, WFRAG(s, t), wk[t], 0, 0, 0);
#pragma unroll
    for (int t = 0; t < 8; ++t) accG[t] = MFMA(a, GFRAG(s, t), accG[t], 0, 0, 0);
  }
#pragma unroll
  for (int t = 0; t < 8; ++t) {
    const float b = b2d[t * 16 + lr];
#pragma unroll
    for (int r = 0; r < 4; ++r) wk[t][r] += b;
  }

  // ---- softmax + cumsum + output; flip(xd) via register permutation ----
  float bg[8];
#pragma unroll
  for (int t = 0; t < 8; ++t) bg[t] = bgp[t * 16 + lr];
#pragma unroll
  for (int r = 0; r < 4; ++r) {
    float lv[8];
#pragma unroll
    for (int t = 0; t < 8; ++t) lv[t] = accG[t][r] + bg[t];
    float m = lv[0];
#pragma unroll
    for (int t = 1; t < 8; ++t) m = fmaxf(m, lv[t]);
#pragma unroll
    for (int d = 1; d < 16; d <<= 1) m = fmaxf(m, __shfl_xor(m, d, 16));
    float g[8];
    float run = 0.f;
#pragma unroll
    for (int t = 0; t < 8; ++t) {
      float p = __expf(lv[t] - m);
      float scn = p;
#pragma unroll
      for (int d = 1; d < 16; d <<= 1) {
        float o = __shfl_up(scn, (unsigned)d, 16);
        if (lr >= d) scn += o;
      }
      g[t] = run + scn;
      run += __shfl(scn, 15, 16);
    }
    const float inv = 1.f / run;
    float xdf[8];
#pragma unroll
    for (int t = 0; t < 8; ++t) xdf[t] = __shfl_xor(wk[7 - t][r], 15, 64);
    const int row = rowbase + lg * 4 + r;
    if (row < N) {
#pragma unroll
      for (int t = 0; t < 8; ++t)
        out[(size_t)row * FF + t * 16 + lr] = sum[t][r] + xdf[t] * (g[t] * inv);
    }
  }
}

extern "C" void kernel_launch(void* const* d_in, const int* in_sizes, int n_in,
                              void* d_out, int out_size, void* d_ws, size_t ws_size,
                              hipStream_t stream) {
  const float* x = (const float*)d_in[0];
  const int* eidx = (const int*)d_in[1];
  const int* etype = (const int*)d_in[2];
  const float* w_sl = (const float*)d_in[3];
  const float* b_sl = (const float*)d_in[4];
  const float* w1n = (const float*)d_in[5];
  const float* b1n = (const float*)d_in[6];
  const float* gamn = (const float*)d_in[7];
  const float* betn = (const float*)d_in[8];
  const float* w2n = (const float*)d_in[9];
  const float* b2n = (const float*)d_in[10];
  const float* w1d = (const float*)d_in[11];
  const float* b1d = (const float*)d_in[12];
  const float* gamd = (const float*)d_in[13];
  const float* betd = (const float*)d_in[14];
  const float* w2d = (const float*)d_in[15];
  const float* b2d = (const float*)d_in[16];
  const float* wgat = (const float*)d_in[17];
  const float* bgat = (const float*)d_in[18];
  float* out = (float*)d_out;

  const int N = in_sizes[0] / FF;
  const int E = in_sizes[2];
  const int* src = eidx;
  const int* dst = eidx + E;
  const int nbins = 2 * N;
  const int nbuckets = (nbins + 511) >> 9;

  const size_t NF = (size_t)N * FF;
  float* gstats = (float*)d_ws;               // 512
  float* bnp = gstats + 512;                  // 512
  float* bgp = bnp + 512;                     // 128
  uint16_t* wbf = (uint16_t*)(bgp + 128);     // 5*16384 u16
  uint16_t* G = wbf + 5 * 16384;              // 3*16384 u16
  uint16_t* xb = G + 3 * 16384;               // NF
  uint16_t* xanb = xb + NF;
  uint16_t* xadb = xanb + NF;
  uint16_t* h1n = xadb + NF;
  uint16_t* h1d = h1n + NF;
  int* hist = (int*)(h1d + NF);
  int* off = hist + nbins;        // nbins+1
  int* ccur = off + nbins + 1;    // nbuckets
  int* bsum = ccur + nbuckets;    // <=1024
  int* ssrc = bsum + 1024;        // E
  uint32_t* bk = (uint32_t*)(ssrc + E);  // E

  const int nb1 = (nbins + 255) / 256;

  hipMemsetAsync(hist, 0, (size_t)nbins * sizeof(int), stream);
  hipMemsetAsync(gstats, 0, 512 * sizeof(float), stream);
  cvt_w_k<<<320, 256, 0, stream>>>(w_sl, w1n, w2n, w1d, w2d, wbf);
  cvt_x_k<<<(int)((NF / 4 + 255) / 256), 256, 0, stream>>>(x, xb, (int)(NF / 4));
  gatepre_k<<<24, 256, 0, stream>>>(wgat, w_sl, w2n, w2d, G);
  bgatp_k<<<1, 128, 0, stream>>>(wgat, b_sl, b2n, b2d, bgat, bgp);

  hist_k<<<(E + 255) / 256, 256, 0, stream>>>(dst, etype, hist, E);
  scan1_k<<<nb1, 256, 0, stream>>>(hist, off, bsum, nbins);
  scan2_k<<<1, 1024, 0, stream>>>(bsum, nb1);
  scan3_k<<<(nbins + 256) / 256, 256, 0, stream>>>(off, ccur, bsum, nbins, E);
  bucketize_k<<<(E + 256 * BK_EPT - 1) / (256 * BK_EPT), 256, 0, stream>>>(
      src, dst, etype, ccur, bk, E, nbuckets);
  sctfine_k<<<nbuckets, 256, 0, stream>>>(off, bk, ssrc, nbins);
  agg_k<<<(nbins + 3) / 4, 256, 0, stream>>>(off, ssrc, xb, xanb, xadb, nbins);

  gemm1_k<<<(N + 255) / 256, 512, 0, stream>>>(xanb, xadb, wbf, b1n, b1d, h1n, h1d,
                                               gstats, N);
  bnfin_k<<<1, 128, 0, stream>>>(gstats, gamn, betn, gamd, betd, bnp, N);
  fuse2_k<<<(N + 127) / 128, 512, 0, stream>>>(xb, h1n, h1d, wbf, G, bnp, b_sl,
                                               b2n, b2d, bgp, out, N);
}